// Round 6
// baseline (1387.899 us; speedup 1.0000x reference)
//
#include <hip/hip_runtime.h>
#include <math.h>

// PrimitiveTokenizer round 6 (diagnostic + restructure):
//  clockprobe: 50k dependent FMAs (~200k cycles) - wall time reveals effective clock.
//  prep:       weights -> bf16 hi/lo MFMA B-fragment planes (unchanged).
//  scan_count: per-row/kind counts + denom + per-(quarter,kind) segment lengths.
//  scan_fill2: compacted VALUES (fp32) + row ids per (1024-slot quarter, kind),
//              padded to x64. No gather needed downstream.
//  mlp2<MODE>: one block per (quarter,kind), 256 thr, 33 KB LDS -> 4 blocks/CU.
//              MODE 0 real, 1 no-trig, 2 const-B (no L2 B loads), 3 front-only.
//              Variants run first (write garbage to poolf), real overwrites.
//  fuse:       unchanged.

// ws layout (byte offsets)
#define W2F_HI   0
#define W2F_LO   524288
#define W1F_HI   1048576
#define W1F_LO   1179648
#define FW1F_HI  1310720
#define FW1F_LO  1507328
#define FW2F_HI  1703936
#define FW2F_LO  1769472
#define POOL_BYTE  3670016ull
#define CNT_BYTE   37224448ull
#define DEN_BYTE   37355520ull
#define VALSC_BYTE 37371904ull
#define ROWSC_BYTE 38944768ull
#define QCNT_BYTE  39337984ull
#define CAP 192

typedef __attribute__((ext_vector_type(8))) short frag;
typedef __attribute__((ext_vector_type(4))) float f32x4;

__device__ __forceinline__ unsigned short f2bf_rn(float x) {
    unsigned int u = __float_as_uint(x);
    unsigned int r = (u + 0x7fffu + ((u >> 16) & 1u)) >> 16;
    return (unsigned short)r;
}
__device__ __forceinline__ float bf2f(unsigned short h) {
    return __uint_as_float(((unsigned int)h) << 16);
}
__device__ __forceinline__ void split_bf(float x, unsigned short& h, unsigned short& l) {
    unsigned short hh = f2bf_rn(x);
    h = hh;
    l = f2bf_rn(x - bf2f(hh));
}

__device__ __forceinline__ float gelu_fast(float x) {
    float u = fabsf(x) * 0.7071067811865476f;
    float t = __builtin_amdgcn_rcpf(fmaf(0.3275911f, u, 1.0f));
    float p = fmaf(fmaf(fmaf(fmaf(1.061405429f, t, -1.453152027f), t,
                             1.421413741f), t, -0.284496736f), t, 0.254829592f) * t;
    float e = __expf(-u * u);
    float er = fmaf(-p, e, 1.0f);
    er = copysignf(er, x);
    return 0.5f * x * (1.0f + er);
}

// ---------------- clock probe ----------------
__global__ void clockprobe_kernel(float* __restrict__ out) {
    float x = 1.0f + (float)threadIdx.x * 1e-7f;
    #pragma unroll 1
    for (int i = 0; i < 50000; ++i) x = fmaf(x, 1.0000001f, 1e-9f);
    out[threadIdx.x] = x;   // overwritten later by real mlp2
}

// ---------------- prep ----------------
__global__ __launch_bounds__(512) void prep_kernel(
    const float* __restrict__ w1, const float* __restrict__ w2,
    const float* __restrict__ fw1, const float* __restrict__ fw2,
    short* __restrict__ ws)
{
    int tid = blockIdx.x * 512 + threadIdx.x;
    int fid = tid >> 6, ln = tid & 63;
    if (fid >= 1792) return;
    int lr = ln & 15, kq = ln >> 4;
    float v[8];
    long long dhi, dlo; int dsto;
    if (fid < 1024) {
        int k = fid >> 7, kst = (fid >> 4) & 7, nt = fid & 15;
        int col = nt * 16 + lr;
        #pragma unroll
        for (int b = 0; b < 8; ++b) {
            int kg = kst * 32 + kq * 8 + b;
            v[b] = w2[(k * 256 + kg) * 256 + col];
        }
        dsto = fid * 512 + ln * 8; dhi = W2F_HI; dlo = W2F_LO;
    } else if (fid < 1280) {
        int f = fid - 1024;
        int k = f >> 5, kst = (f >> 4) & 1, nt = f & 15;
        int col = nt * 16 + lr;
        #pragma unroll
        for (int b = 0; b < 8; ++b) {
            int kg = kst * 32 + kq * 8 + b;
            v[b] = (kg < 48) ? w1[(k * 48 + kg) * 256 + col] : 0.0f;
        }
        dsto = f * 512 + ln * 8; dhi = W1F_HI; dlo = W1F_LO;
    } else if (fid < 1664) {
        int f = fid - 1280;
        int kst = f >> 4, nt = f & 15;
        int col = nt * 16 + lr;
        #pragma unroll
        for (int b = 0; b < 8; ++b) {
            int kg = kst * 32 + kq * 8 + b;
            v[b] = fw1[kg * 256 + col];
        }
        dsto = f * 512 + ln * 8; dhi = FW1F_HI; dlo = FW1F_LO;
    } else {
        int f = fid - 1664;
        int kst = f >> 4, nt = f & 15;
        int col = nt * 16 + lr;
        #pragma unroll
        for (int b = 0; b < 8; ++b) {
            int kg = kst * 32 + kq * 8 + b;
            v[b] = fw2[kg * 256 + col];
        }
        dsto = f * 512 + ln * 8; dhi = FW2F_HI; dlo = FW2F_LO;
    }
    union { unsigned short u[8]; frag f; } hu, lu;
    #pragma unroll
    for (int b = 0; b < 8; ++b) split_bf(v[b], hu.u[b], lu.u[b]);
    *(frag*)((short*)((char*)ws + dhi * 2) + dsto) = hu.f;
    *(frag*)((short*)((char*)ws + dlo * 2) + dsto) = lu.f;
}

// ---------------- scan pass 1: counts ----------------
__global__ __launch_bounds__(256) void scan_count(
    const int* __restrict__ kinds, const int* __restrict__ mask,
    float* __restrict__ cntf, float* __restrict__ denf,
    int* __restrict__ qcnt)
{
    __shared__ int qc[8];
    const int t = threadIdx.x, b = blockIdx.x;
    const int wv = t >> 6, ln = t & 63;
    if (t < 8) qc[t] = 0;
    __syncthreads();

    for (int j = 0; j < 4; ++j) {
        int R = b * 16 + wv * 4 + j;
        int kd = kinds[R * 64 + ln];
        int mk = mask[R * 64 + ln];
        unsigned long long mb = __ballot(mk != 0);
        int tot = __popcll(mb);
        int myc = 0;
        #pragma unroll
        for (int k = 0; k < 8; ++k) {
            unsigned long long bal = __ballot(mk && (kd == k));
            int c = __popcll(bal);
            myc = (ln == k) ? c : myc;
        }
        if (ln < 8) {
            cntf[R * 8 + ln] = (float)myc;
            atomicAdd(&qc[ln], myc);
        }
        if (ln == 0) denf[R] = 1.0f / (float)(tot > 0 ? tot : 1);
    }
    __syncthreads();
    if (t < 8) qcnt[b * 8 + t] = qc[t];
}

// ---------------- scan pass 2: compacted values + rows ----------------
__global__ __launch_bounds__(256) void scan_fill2(
    const int* __restrict__ kinds, const int* __restrict__ mask,
    const float* __restrict__ values,
    float* __restrict__ vals_c, unsigned char* __restrict__ rows_c)
{
    const int t = threadIdx.x, b = blockIdx.x;
    const int wv = t >> 6, ln = t & 63;
    const unsigned long long below = (1ull << ln) - 1ull;

    for (int half = 0; half < 2; ++half) {
        const int k = wv * 2 + half;
        int fill = 0;
        float* vp = vals_c + (b * 8 + k) * CAP;
        unsigned char* rp = rows_c + (b * 8 + k) * CAP;
        for (int c = 0; c < 16; ++c) {
            int p = c * 64 + ln;
            int gs = b * 1024 + p;
            int kd = kinds[gs], mk = mask[gs];
            unsigned long long bal = __ballot(mk && (kd == k));
            if (mk && (kd == k)) {
                int idx = fill + __popcll(bal & below);
                if (idx < CAP) { vp[idx] = values[gs]; rp[idx] = (unsigned char)(p >> 6); }
            }
            fill += __popcll(bal);
        }
        int fl = min(fill, CAP);
        int lp64 = (fl + 63) & ~63;
        for (int i = fl + ln; i < lp64; i += 64) { vp[i] = 0.0f; rp[i] = 0xFFu; }
    }
}

// ---------------- mlp2: one block per (quarter, kind) ----------------
// MODE: 0 real, 1 no-trig, 2 const-B, 3 front-only
template<int MODE>
__global__ __launch_bounds__(256) void mlp2_kernel(
    const float* __restrict__ vals_c, const unsigned char* __restrict__ rows_c,
    const int* __restrict__ qcnt, const short* __restrict__ wsf,
    const float* __restrict__ B_ff, const float* __restrict__ b1,
    float* __restrict__ poolf)
{
    __shared__ __align__(16) short At[2][4096];   // 16 KB (hi/lo A-tile, swizzled)
    __shared__ float pool[16 * 257];              // 16.4 KB
    __shared__ unsigned short rows_t[64];
    __shared__ float Bs[24];

    const int t = threadIdx.x, blk = blockIdx.x;
    const int b = blk >> 3, k = blk & 7;
    const int wv = t >> 6, ln = t & 63, lr16 = ln & 15, kq = ln >> 4;
    const int seg = b * 8 + k;

    const short* w1f_hi = (const short*)((const char*)wsf + W1F_HI * 2);
    const short* w1f_lo = (const short*)((const char*)wsf + W1F_LO * 2);

    if (t < 24) Bs[t] = B_ff[t];
    for (int i = t; i < 16 * 257; i += 256) pool[i] = 0.0f;

    const int len = qcnt[seg];
    const int ntl = min((len + 63) >> 6, CAP / 64);

    float b1r[16];
    #pragma unroll
    for (int nt = 0; nt < 16; ++nt) b1r[nt] = b1[k * 256 + nt * 16 + lr16];

    __syncthreads();

    for (int m = 0; m < ntl; ++m) {
        // ---- FF phase ----
        if (t < 64) rows_t[t] = (unsigned short)rows_c[seg * CAP + m * 64 + t];
        #pragma unroll
        for (int it = 0; it < 2; ++it) {
            int item = t + it * 256;
            int s = item >> 3, g = item & 7;
            union { unsigned short u[8]; frag f; } hu, lu;
            if (g < 6) {
                float v = vals_c[seg * CAP + m * 64 + s];
                int iscos = (g >= 3);
                int j0 = (iscos ? (g - 3) : g) * 8;
                #pragma unroll
                for (int bb = 0; bb < 8; ++bb) {
                    float sv;
                    if (MODE == 1) {
                        sv = v * Bs[j0 + bb];
                    } else {
                        float rev = __builtin_amdgcn_fractf(v * Bs[j0 + bb]);
                        sv = iscos ? __builtin_amdgcn_cosf(rev)
                                   : __builtin_amdgcn_sinf(rev);
                    }
                    split_bf(sv, hu.u[bb], lu.u[bb]);
                }
            } else {
                #pragma unroll
                for (int bb = 0; bb < 8; ++bb) { hu.u[bb] = 0; lu.u[bb] = 0; }
            }
            int ao = s * 64 + ((g ^ (s & 7)) << 3);
            *(frag*)&At[0][ao] = hu.f;
            *(frag*)&At[1][ao] = lu.f;
        }
        __syncthreads();

        // ---- back half ----
        frag ah[2], al[2];
        #pragma unroll
        for (int kst = 0; kst < 2; ++kst) {
            int gi = kst * 4 + kq;
            int ao = (wv * 16 + lr16) * 64 + ((gi ^ (lr16 & 7)) << 3);
            ah[kst] = *(const frag*)&At[0][ao];
            al[kst] = *(const frag*)&At[1][ao];
        }

        if (MODE == 3) {
            asm volatile("" :: "v"((int)(ah[0][0] + ah[1][0] + al[0][0] + al[1][0])));
        } else {
            unsigned short e4[4];
            #pragma unroll
            for (int r = 0; r < 4; ++r) e4[r] = rows_t[wv * 16 + kq * 4 + r];

            for (int nt = 0; nt < 16; ++nt) {
                frag bh0, bl0, bh1, bl1;
                if (MODE == 2) {
                    union { unsigned short u[8]; frag f; } cb;
                    #pragma unroll
                    for (int bb = 0; bb < 8; ++bb) cb.u[bb] = (unsigned short)(0x3F80 + nt + bb);
                    bh0 = cb.f; bl0 = cb.f; bh1 = cb.f; bl1 = cb.f;
                } else {
                    int o0 = ((k * 2 + 0) * 16 + nt) * 512 + ln * 8;
                    int o1 = ((k * 2 + 1) * 16 + nt) * 512 + ln * 8;
                    bh0 = *(const frag*)(w1f_hi + o0);
                    bl0 = *(const frag*)(w1f_lo + o0);
                    bh1 = *(const frag*)(w1f_hi + o1);
                    bl1 = *(const frag*)(w1f_lo + o1);
                }
                f32x4 acc = (f32x4)0.0f;
                acc = __builtin_amdgcn_mfma_f32_16x16x32_bf16(ah[0], bh0, acc, 0, 0, 0);
                acc = __builtin_amdgcn_mfma_f32_16x16x32_bf16(al[0], bh0, acc, 0, 0, 0);
                acc = __builtin_amdgcn_mfma_f32_16x16x32_bf16(ah[0], bl0, acc, 0, 0, 0);
                acc = __builtin_amdgcn_mfma_f32_16x16x32_bf16(ah[1], bh1, acc, 0, 0, 0);
                acc = __builtin_amdgcn_mfma_f32_16x16x32_bf16(al[1], bh1, acc, 0, 0, 0);
                acc = __builtin_amdgcn_mfma_f32_16x16x32_bf16(ah[1], bl1, acc, 0, 0, 0);
                #pragma unroll
                for (int r = 0; r < 4; ++r) {
                    unsigned short e = e4[r];
                    if (e != 0xFFu) {
                        float g = gelu_fast(acc[r] + b1r[nt]);
                        atomicAdd(&pool[e * 257 + nt * 16 + lr16], g);
                    }
                }
            }
        }
        __syncthreads();
    }

    // flush (block-exclusive)
    for (int i = t; i < 16 * 256; i += 256) {
        int r = i >> 8, c = i & 255;
        poolf[((size_t)k * 4096 + b * 16 + r) * 256 + c] = pool[r * 257 + c];
    }
}

// ---------------- fuse kernel (unchanged) ----------------
__global__ __launch_bounds__(512) void fuse_kernel(
    const short* __restrict__ ws, const float* __restrict__ poolf,
    const float* __restrict__ cntf, const float* __restrict__ denf,
    const int* __restrict__ pt, const int* __restrict__ lid,
    const float* __restrict__ meta, const float* __restrict__ type_emb,
    const float* __restrict__ layer_emb, const float* __restrict__ b2,
    const float* __restrict__ kind_emb, const float* __restrict__ fb1,
    const float* __restrict__ fb2, const float* __restrict__ meta_w,
    const float* __restrict__ meta_b, float* __restrict__ out)
{
    __shared__ __align__(16) short Af[2][2][4096];
    __shared__ __align__(16) float hz[4096];
    __shared__ float cnt_s[128], den_s[16], meta_s[64];
    __shared__ int pt_s[16], lid_s[16];

    const short* w2f_hi  = (const short*)((const char*)ws + W2F_HI * 2);
    const short* w2f_lo  = (const short*)((const char*)ws + W2F_LO * 2);
    const short* fw1f_hi = (const short*)((const char*)ws + FW1F_HI * 2);
    const short* fw1f_lo = (const short*)((const char*)ws + FW1F_LO * 2);
    const short* fw2f_hi = (const short*)((const char*)ws + FW2F_HI * 2);
    const short* fw2f_lo = (const short*)((const char*)ws + FW2F_LO * 2);

    const int t = threadIdx.x, blk = blockIdx.x, rb = blk * 16;
    const int wv = t >> 6, ln = t & 63, lr16 = ln & 15, kq = ln >> 4;

    if (t < 16) { pt_s[t] = pt[rb + t]; lid_s[t] = lid[rb + t]; den_s[t] = denf[rb + t]; }
    else if (t < 144) cnt_s[t - 16] = cntf[rb * 8 + (t - 16)];
    else if (t < 208) meta_s[t - 144] = meta[rb * 4 + (t - 144)];

    const int sr = t >> 5, sg = t & 31;
    const int skst = sg >> 2, skq = sg & 3;
    const int slane = skq * 16 + sr;
    const int sdst = slane * 64 + ((skst ^ (sr & 7)) << 3);

    auto stage = [&](int k, int buf) {
        const float* src = poolf + ((size_t)k * 4096 + rb + sr) * 256 + sg * 8;
        f32x4 u0 = *(const f32x4*)src;
        f32x4 u1 = *(const f32x4*)(src + 4);
        union { unsigned short u[8]; frag f; } hu, lu;
        #pragma unroll
        for (int b = 0; b < 4; ++b) {
            split_bf(u0[b], hu.u[b], lu.u[b]);
            split_bf(u1[b], hu.u[b + 4], lu.u[b + 4]);
        }
        *(frag*)&Af[buf][0][sdst] = hu.f;
        *(frag*)&Af[buf][1][sdst] = lu.f;
    };

    stage(0, 0);
    __syncthreads();

    f32x4 acc[2];
    acc[0] = (f32x4)0.0f; acc[1] = (f32x4)0.0f;

    for (int k = 0; k < 8; ++k) {
        const int buf = k & 1;
        if (k < 7) stage(k + 1, buf ^ 1);
        #pragma unroll 2
        for (int kst = 0; kst < 8; ++kst) {
            int ao = ln * 64 + ((kst ^ (ln & 7)) << 3);
            frag ah = *(const frag*)&Af[buf][0][ao];
            frag al = *(const frag*)&Af[buf][1][ao];
            #pragma unroll
            for (int n = 0; n < 2; ++n) {
                size_t bo = (((size_t)k * 8 + kst) * 16 + (wv * 2 + n)) * 512 + ln * 8;
                frag bh = *(const frag*)(w2f_hi + bo);
                frag bl = *(const frag*)(w2f_lo + bo);
                acc[n] = __builtin_amdgcn_mfma_f32_16x16x32_bf16(ah, bh, acc[n], 0, 0, 0);
                acc[n] = __builtin_amdgcn_mfma_f32_16x16x32_bf16(al, bh, acc[n], 0, 0, 0);
                acc[n] = __builtin_amdgcn_mfma_f32_16x16x32_bf16(ah, bl, acc[n], 0, 0, 0);
            }
        }
        __syncthreads();
    }

    #pragma unroll
    for (int n = 0; n < 2; ++n) {
        int col = (wv * 2 + n) * 16 + lr16;
        float bks[8];
        #pragma unroll
        for (int k = 0; k < 8; ++k) bks[k] = b2[k * 256 + col] + kind_emb[k * 256 + col];
        #pragma unroll
        for (int r = 0; r < 4; ++r) {
            int row = kq * 4 + r;
            float hv = acc[n][r];
            #pragma unroll
            for (int k = 0; k < 8; ++k) hv = fmaf(cnt_s[row * 8 + k], bks[k], hv);
            hv *= den_s[row];
            hz[row * 256 + ((((col >> 2) ^ (row & 7)) << 2) | (col & 3))] = hv;
        }
    }
    __syncthreads();

    f32x4 az[2];
    az[0] = (f32x4)0.0f; az[1] = (f32x4)0.0f;

    for (int kst = 0; kst < 24; ++kst) {
        const int row = lr16;
        union { unsigned short u[8]; frag f; } hu, lu;
        if (kst < 8) {
            int c0 = kst * 8 + kq * 2;
            f32x4 u0 = *(const f32x4*)&hz[row * 256 + ((c0 ^ (row & 7)) << 2)];
            f32x4 u1 = *(const f32x4*)&hz[row * 256 + (((c0 + 1) ^ (row & 7)) << 2)];
            #pragma unroll
            for (int b = 0; b < 4; ++b) {
                split_bf(u0[b], hu.u[b], lu.u[b]);
                split_bf(u1[b], hu.u[b + 4], lu.u[b + 4]);
            }
        } else {
            const float* eb = (kst < 16) ? type_emb : layer_emb;
            const int* ids = (kst < 16) ? pt_s : lid_s;
            int ko = (kst & 7) * 32 + kq * 8;
            const float* sp = eb + (size_t)ids[row] * 256 + ko;
            f32x4 u0 = *(const f32x4*)sp;
            f32x4 u1 = *(const f32x4*)(sp + 4);
            #pragma unroll
            for (int b = 0; b < 4; ++b) {
                split_bf(u0[b], hu.u[b], lu.u[b]);
                split_bf(u1[b], hu.u[b + 4], lu.u[b + 4]);
            }
        }
        frag ah = hu.f, al = lu.f;
        #pragma unroll
        for (int n = 0; n < 2; ++n) {
            size_t bo = ((size_t)kst * 16 + (wv * 2 + n)) * 512 + ln * 8;
            frag bh = *(const frag*)(fw1f_hi + bo);
            frag bl = *(const frag*)(fw1f_lo + bo);
            az[n] = __builtin_amdgcn_mfma_f32_16x16x32_bf16(ah, bh, az[n], 0, 0, 0);
            az[n] = __builtin_amdgcn_mfma_f32_16x16x32_bf16(al, bh, az[n], 0, 0, 0);
            az[n] = __builtin_amdgcn_mfma_f32_16x16x32_bf16(ah, bl, az[n], 0, 0, 0);
        }
    }
    __syncthreads();

    #pragma unroll
    for (int n = 0; n < 2; ++n) {
        int col = (wv * 2 + n) * 16 + lr16;
        float fb1v = fb1[col];
        #pragma unroll
        for (int r = 0; r < 4; ++r) {
            int row = kq * 4 + r;
            float z = gelu_fast(az[n][r] + fb1v);
            hz[row * 256 + ((((col >> 2) ^ (row & 7)) << 2) | (col & 3))] = z;
        }
    }
    __syncthreads();

    f32x4 ao2[2];
    ao2[0] = (f32x4)0.0f; ao2[1] = (f32x4)0.0f;

    for (int kst = 0; kst < 8; ++kst) {
        const int row = lr16;
        int c0 = kst * 8 + kq * 2;
        f32x4 u0 = *(const f32x4*)&hz[row * 256 + ((c0 ^ (row & 7)) << 2)];
        f32x4 u1 = *(const f32x4*)&hz[row * 256 + (((c0 + 1) ^ (row & 7)) << 2)];
        union { unsigned short u[8]; frag f; } hu, lu;
        #pragma unroll
        for (int b = 0; b < 4; ++b) {
            split_bf(u0[b], hu.u[b], lu.u[b]);
            split_bf(u1[b], hu.u[b + 4], lu.u[b + 4]);
        }
        frag ah = hu.f, al = lu.f;
        #pragma unroll
        for (int n = 0; n < 2; ++n) {
            size_t bo = ((size_t)kst * 16 + (wv * 2 + n)) * 512 + ln * 8;
            frag bh = *(const frag*)(fw2f_hi + bo);
            frag bl = *(const frag*)(fw2f_lo + bo);
            ao2[n] = __builtin_amdgcn_mfma_f32_16x16x32_bf16(ah, bh, ao2[n], 0, 0, 0);
            ao2[n] = __builtin_amdgcn_mfma_f32_16x16x32_bf16(al, bh, ao2[n], 0, 0, 0);
            ao2[n] = __builtin_amdgcn_mfma_f32_16x16x32_bf16(ah, bl, ao2[n], 0, 0, 0);
        }
    }

    #pragma unroll
    for (int n = 0; n < 2; ++n) {
        int col = (wv * 2 + n) * 16 + lr16;
        float ob = fb2[col] + meta_b[col];
        float mw0 = meta_w[col], mw1 = meta_w[256 + col];
        float mw2 = meta_w[512 + col], mw3 = meta_w[768 + col];
        #pragma unroll
        for (int r = 0; r < 4; ++r) {
            int row = kq * 4 + r;
            float o = ao2[n][r] + ob;
            o = fmaf(meta_s[row * 4 + 0], mw0, o);
            o = fmaf(meta_s[row * 4 + 1], mw1, o);
            o = fmaf(meta_s[row * 4 + 2], mw2, o);
            o = fmaf(meta_s[row * 4 + 3], mw3, o);
            out[(size_t)(rb + row) * 256 + col] = o;
        }
    }
}

extern "C" void kernel_launch(void* const* d_in, const int* in_sizes, int n_in,
                              void* d_out, int out_size, void* d_ws, size_t ws_size,
                              hipStream_t stream) {
    const float* values    = (const float*)d_in[0];
    const int*   kinds     = (const int*)d_in[1];
    const int*   mask      = (const int*)d_in[2];
    const int*   prim_type = (const int*)d_in[3];
    const int*   layer_id  = (const int*)d_in[4];
    const float* meta      = (const float*)d_in[5];
    const float* B_ff      = (const float*)d_in[6];
    const float* kind_emb  = (const float*)d_in[7];
    const float* type_emb  = (const float*)d_in[8];
    const float* layer_emb = (const float*)d_in[9];
    const float* mlp_w1    = (const float*)d_in[10];
    const float* mlp_b1    = (const float*)d_in[11];
    const float* mlp_w2    = (const float*)d_in[12];
    const float* mlp_b2    = (const float*)d_in[13];
    const float* fuse_w1   = (const float*)d_in[14];
    const float* fuse_b1   = (const float*)d_in[15];
    const float* fuse_w2   = (const float*)d_in[16];
    const float* fuse_b2   = (const float*)d_in[17];
    const float* meta_w    = (const float*)d_in[18];
    const float* meta_b    = (const float*)d_in[19];

    short*          ws     = (short*)d_ws;
    float*          poolf  = (float*)((char*)d_ws + POOL_BYTE);
    float*          cntf   = (float*)((char*)d_ws + CNT_BYTE);
    float*          denf   = (float*)((char*)d_ws + DEN_BYTE);
    float*          vals_c = (float*)((char*)d_ws + VALSC_BYTE);
    unsigned char*  rows_c = (unsigned char*)((char*)d_ws + ROWSC_BYTE);
    int*            qcnt   = (int*)((char*)d_ws + QCNT_BYTE);
    float*          out    = (float*)d_out;

    clockprobe_kernel<<<1, 64, 0, stream>>>(poolf);
    prep_kernel<<<224, 512, 0, stream>>>(mlp_w1, mlp_w2, fuse_w1, fuse_w2, ws);
    scan_count<<<256, 256, 0, stream>>>(kinds, mask, cntf, denf, qcnt);
    scan_fill2<<<256, 256, 0, stream>>>(kinds, mask, values, vals_c, rows_c);
    // ablation variants (write garbage pool; real run overwrites everything)
    mlp2_kernel<1><<<2048, 256, 0, stream>>>(vals_c, rows_c, qcnt, ws, B_ff, mlp_b1, poolf);
    mlp2_kernel<2><<<2048, 256, 0, stream>>>(vals_c, rows_c, qcnt, ws, B_ff, mlp_b1, poolf);
    mlp2_kernel<3><<<2048, 256, 0, stream>>>(vals_c, rows_c, qcnt, ws, B_ff, mlp_b1, poolf);
    // real
    mlp2_kernel<0><<<2048, 256, 0, stream>>>(vals_c, rows_c, qcnt, ws, B_ff, mlp_b1, poolf);
    fuse_kernel<<<256, 512, 0, stream>>>(ws, poolf, cntf, denf, prim_type, layer_id,
                                         meta, type_emb, layer_emb, mlp_b2, kind_emb,
                                         fuse_b1, fuse_b2, meta_w, meta_b, out);
}

// Round 7
// 306.664 us; speedup vs baseline: 4.5258x; 4.5258x over previous
//
#include <hip/hip_runtime.h>
#include <math.h>

// PrimitiveTokenizer round 7:
//  prep:      4 weight matrices -> bf16 hi/lo MFMA B-fragment planes (as before).
//  mlpfused:  2048 blocks x 256 thr, one block per (1024-slot quarter, kind).
//             In-block: stage vals/kinds/mask -> per-row counts + denom ->
//             wave-0 ballot compaction (deterministic) -> wave-strided 16-slot
//             tiles with FF computed DIRECTLY INTO A-FRAGMENT REGISTERS
//             (no LDS staging, no main-loop barriers) -> 6 MFMA x 16 nt ->
//             gelu -> LDS fp32 atomic pool -> flush to poolf.
//             MODE 3 = front-only ablation (runs first, overwritten by MODE 0).
//  fuse:      unchanged (GEMM2 batched over kinds + fuse MLP + meta linear).

// ws layout (short element offsets for frag planes; byte offsets otherwise)
#define W2F_HI   0
#define W2F_LO   524288
#define W1F_HI   1048576
#define W1F_LO   1179648
#define FW1F_HI  1310720
#define FW1F_LO  1507328
#define FW2F_HI  1703936
#define FW2F_LO  1769472
#define POOL_BYTE  3670016ull
#define CNT_BYTE   37224448ull
#define DEN_BYTE   37355520ull

typedef __attribute__((ext_vector_type(8))) short frag;
typedef __attribute__((ext_vector_type(4))) float f32x4;

__device__ __forceinline__ unsigned short f2bf_rn(float x) {
    unsigned int u = __float_as_uint(x);
    unsigned int r = (u + 0x7fffu + ((u >> 16) & 1u)) >> 16;
    return (unsigned short)r;
}
__device__ __forceinline__ float bf2f(unsigned short h) {
    return __uint_as_float(((unsigned int)h) << 16);
}
__device__ __forceinline__ void split_bf(float x, unsigned short& h, unsigned short& l) {
    unsigned short hh = f2bf_rn(x);
    h = hh;
    l = f2bf_rn(x - bf2f(hh));
}

// |abs err| <= ~1.5e-7 (A&S 7.1.26 erf)
__device__ __forceinline__ float gelu_fast(float x) {
    float u = fabsf(x) * 0.7071067811865476f;
    float t = __builtin_amdgcn_rcpf(fmaf(0.3275911f, u, 1.0f));
    float p = fmaf(fmaf(fmaf(fmaf(1.061405429f, t, -1.453152027f), t,
                             1.421413741f), t, -0.284496736f), t, 0.254829592f) * t;
    float e = __expf(-u * u);
    float er = fmaf(-p, e, 1.0f);
    er = copysignf(er, x);
    return 0.5f * x * (1.0f + er);
}

// ---------------- prep: weights -> bf16 hi/lo fragment planes ----------------
__global__ __launch_bounds__(512) void prep_kernel(
    const float* __restrict__ w1, const float* __restrict__ w2,
    const float* __restrict__ fw1, const float* __restrict__ fw2,
    short* __restrict__ ws)
{
    int tid = blockIdx.x * 512 + threadIdx.x;
    int fid = tid >> 6, ln = tid & 63;
    if (fid >= 1792) return;
    int lr = ln & 15, kq = ln >> 4;
    float v[8];
    int dhi, dlo, dsto;
    if (fid < 1024) {                       // w2: [8k][8kst][16nt]
        int k = fid >> 7, kst = (fid >> 4) & 7, nt = fid & 15;
        int col = nt * 16 + lr;
        #pragma unroll
        for (int b = 0; b < 8; ++b) {
            int kg = kst * 32 + kq * 8 + b;
            v[b] = w2[(k * 256 + kg) * 256 + col];
        }
        dsto = fid * 512 + ln * 8; dhi = W2F_HI; dlo = W2F_LO;
    } else if (fid < 1280) {                // w1: [8k][2kst][16nt], K pad 48->64
        int f = fid - 1024;
        int k = f >> 5, kst = (f >> 4) & 1, nt = f & 15;
        int col = nt * 16 + lr;
        #pragma unroll
        for (int b = 0; b < 8; ++b) {
            int kg = kst * 32 + kq * 8 + b;
            v[b] = (kg < 48) ? w1[(k * 48 + kg) * 256 + col] : 0.0f;
        }
        dsto = f * 512 + ln * 8; dhi = W1F_HI; dlo = W1F_LO;
    } else if (fid < 1664) {                // fw1: [24kst][16nt]
        int f = fid - 1280;
        int kst = f >> 4, nt = f & 15;
        int col = nt * 16 + lr;
        #pragma unroll
        for (int b = 0; b < 8; ++b) {
            int kg = kst * 32 + kq * 8 + b;
            v[b] = fw1[kg * 256 + col];
        }
        dsto = f * 512 + ln * 8; dhi = FW1F_HI; dlo = FW1F_LO;
    } else {                                // fw2: [8kst][16nt]
        int f = fid - 1664;
        int kst = f >> 4, nt = f & 15;
        int col = nt * 16 + lr;
        #pragma unroll
        for (int b = 0; b < 8; ++b) {
            int kg = kst * 32 + kq * 8 + b;
            v[b] = fw2[kg * 256 + col];
        }
        dsto = f * 512 + ln * 8; dhi = FW2F_HI; dlo = FW2F_LO;
    }
    union { unsigned short u[8]; frag f; } hu, lu;
    #pragma unroll
    for (int b = 0; b < 8; ++b) split_bf(v[b], hu.u[b], lu.u[b]);
    *(frag*)(ws + dhi + dsto) = hu.f;
    *(frag*)(ws + dlo + dsto) = lu.f;
}

// ---------------- mlpfused: one block per (quarter, kind) ----------------
// MODE: 0 real, 3 front-only (FF kept live, back half skipped)
template<int MODE>
__global__ __launch_bounds__(256, 4) void mlpfused_kernel(
    const float* __restrict__ values, const int* __restrict__ kinds,
    const int* __restrict__ mask, const short* __restrict__ wsf,
    const float* __restrict__ B_ff, const float* __restrict__ b1,
    float* __restrict__ poolf, float* __restrict__ cntf,
    float* __restrict__ denf)
{
    __shared__ float vals_ls[1024];                 // 4 KB
    __shared__ unsigned char knd_ls[1024], msk_ls[1024];
    __shared__ unsigned short list[1088];
    __shared__ int len_s;
    __shared__ float pool[16 * 257];                // 16.4 KB
    __shared__ float Bs_ls[24], b1_ls[256];

    const int t = threadIdx.x, blk = blockIdx.x;
    const int q = blk >> 3, k = blk & 7;
    const int wv = t >> 6, ln = t & 63, lr16 = ln & 15, kq = ln >> 4;
    const int gbase = q * 1024;

    const short* w1f_hi = wsf + W1F_HI;
    const short* w1f_lo = wsf + W1F_LO;

    // ---- stage ----
    #pragma unroll
    for (int i = 0; i < 4; ++i) {
        int p = t + i * 256;
        vals_ls[p] = values[gbase + p];
        knd_ls[p]  = (unsigned char)kinds[gbase + p];
        msk_ls[p]  = (unsigned char)mask[gbase + p];
    }
    if (t < 24) Bs_ls[t] = B_ff[t];
    b1_ls[t] = b1[k * 256 + t];
    for (int i = t; i < 16 * 257; i += 256) pool[i] = 0.0f;
    __syncthreads();

    // ---- per-row counts + denom (wave wv handles rows wv*4..wv*4+3) ----
    #pragma unroll
    for (int j = 0; j < 4; ++j) {
        int r = wv * 4 + j;
        int kd = knd_ls[r * 64 + ln], mk = msk_ls[r * 64 + ln];
        unsigned long long balk = __ballot(mk && (kd == k));
        unsigned long long balm = __ballot(mk != 0);
        if (ln == 0) {
            cntf[(q * 16 + r) * 8 + k] = (float)__popcll(balk);
            if (k == 0) {
                int tot = __popcll(balm);
                denf[q * 16 + r] = 1.0f / (float)(tot > 0 ? tot : 1);
            }
        }
    }

    // ---- deterministic compaction (wave 0) ----
    if (t < 64) {
        const unsigned long long below = (1ull << ln) - 1ull;
        int fill = 0;
        for (int c = 0; c < 16; ++c) {
            int p = c * 64 + ln;
            int kd = knd_ls[p], mk = msk_ls[p];
            unsigned long long bal = __ballot(mk && (kd == k));
            if (mk && (kd == k)) list[fill + __popcll(bal & below)] = (unsigned short)p;
            fill += __popcll(bal);
        }
        if (ln == 0) len_s = fill;
        int pad = (fill + 63) & ~63;
        for (int i = fill + ln; i < pad; i += 64) list[i] = 0xFFFFu;
    }
    __syncthreads();

    const int ntl = (len_s + 15) >> 4;

    // ---- barrier-free main loop: wave-strided 16-slot tiles ----
    for (int m = wv; m < ntl; m += 4) {
        int slot = list[m * 16 + lr16];
        float v = vals_ls[slot & 1023];
        v = (slot == 0xFFFFu) ? 0.0f : v;

        // FF directly into A-fragment registers: lane(lr16,kq) holds
        // A[slot=lr16][feat = kst*32 + kq*8 + b]
        frag ah[2], al[2];
        #pragma unroll
        for (int kst = 0; kst < 2; ++kst) {
            union { unsigned short u[8]; frag f; } hu, lu;
            int jb0 = kst * 32 + kq * 8;
            #pragma unroll
            for (int b = 0; b < 8; ++b) {
                int jb = jb0 + b;
                float sv;
                if (jb < 48) {
                    int jm = (jb < 24) ? jb : jb - 24;
                    float cadd = (jb < 24) ? 0.0f : 0.25f;   // cos = sin(x+1/4 rev)
                    float rev = __builtin_amdgcn_fractf(fmaf(v, Bs_ls[jm], cadd));
                    sv = __builtin_amdgcn_sinf(rev);
                } else {
                    sv = 0.0f;                               // K-pad 48..63
                }
                split_bf(sv, hu.u[b], lu.u[b]);
            }
            ah[kst] = hu.f; al[kst] = lu.f;
        }

        if (MODE == 3) {
            asm volatile("" :: "v"((int)ah[0][0]), "v"((int)ah[1][0]),
                              "v"((int)al[0][0]), "v"((int)al[1][0]));
            continue;
        }

        int e4[4];
        #pragma unroll
        for (int r = 0; r < 4; ++r) {
            int sl = list[m * 16 + kq * 4 + r];
            e4[r] = (sl == 0xFFFFu) ? -1 : (sl >> 6);
        }

        #pragma unroll 4
        for (int nt = 0; nt < 16; ++nt) {
            int o0 = ((k * 2 + 0) * 16 + nt) * 512 + ln * 8;
            int o1 = ((k * 2 + 1) * 16 + nt) * 512 + ln * 8;
            frag bh0 = *(const frag*)(w1f_hi + o0);
            frag bl0 = *(const frag*)(w1f_lo + o0);
            frag bh1 = *(const frag*)(w1f_hi + o1);
            frag bl1 = *(const frag*)(w1f_lo + o1);
            f32x4 acc = (f32x4)0.0f;
            acc = __builtin_amdgcn_mfma_f32_16x16x32_bf16(ah[0], bh0, acc, 0, 0, 0);
            acc = __builtin_amdgcn_mfma_f32_16x16x32_bf16(al[0], bh0, acc, 0, 0, 0);
            acc = __builtin_amdgcn_mfma_f32_16x16x32_bf16(ah[0], bl0, acc, 0, 0, 0);
            acc = __builtin_amdgcn_mfma_f32_16x16x32_bf16(ah[1], bh1, acc, 0, 0, 0);
            acc = __builtin_amdgcn_mfma_f32_16x16x32_bf16(al[1], bh1, acc, 0, 0, 0);
            acc = __builtin_amdgcn_mfma_f32_16x16x32_bf16(ah[1], bl1, acc, 0, 0, 0);
            float b1v = b1_ls[nt * 16 + lr16];
            #pragma unroll
            for (int r = 0; r < 4; ++r) {
                if (e4[r] >= 0) {
                    float g = gelu_fast(acc[r] + b1v);
                    atomicAdd(&pool[e4[r] * 257 + nt * 16 + lr16], g);
                }
            }
        }
    }
    __syncthreads();

    // ---- flush (block-exclusive) ----
    for (int i = t; i < 16 * 256; i += 256) {
        int r = i >> 8, c = i & 255;
        poolf[((size_t)k * 4096 + q * 16 + r) * 256 + c] = pool[r * 257 + c];
    }
}

// ---------------- fuse kernel (unchanged) ----------------
__global__ __launch_bounds__(512) void fuse_kernel(
    const short* __restrict__ ws, const float* __restrict__ poolf,
    const float* __restrict__ cntf, const float* __restrict__ denf,
    const int* __restrict__ pt, const int* __restrict__ lid,
    const float* __restrict__ meta, const float* __restrict__ type_emb,
    const float* __restrict__ layer_emb, const float* __restrict__ b2,
    const float* __restrict__ kind_emb, const float* __restrict__ fb1,
    const float* __restrict__ fb2, const float* __restrict__ meta_w,
    const float* __restrict__ meta_b, float* __restrict__ out)
{
    __shared__ __align__(16) short Af[2][2][4096];
    __shared__ __align__(16) float hz[4096];
    __shared__ float cnt_s[128], den_s[16], meta_s[64];
    __shared__ int pt_s[16], lid_s[16];

    const short* w2f_hi  = ws + W2F_HI;
    const short* w2f_lo  = ws + W2F_LO;
    const short* fw1f_hi = ws + FW1F_HI;
    const short* fw1f_lo = ws + FW1F_LO;
    const short* fw2f_hi = ws + FW2F_HI;
    const short* fw2f_lo = ws + FW2F_LO;

    const int t = threadIdx.x, blk = blockIdx.x, rb = blk * 16;
    const int wv = t >> 6, ln = t & 63, lr16 = ln & 15, kq = ln >> 4;

    if (t < 16) { pt_s[t] = pt[rb + t]; lid_s[t] = lid[rb + t]; den_s[t] = denf[rb + t]; }
    else if (t < 144) cnt_s[t - 16] = cntf[rb * 8 + (t - 16)];
    else if (t < 208) meta_s[t - 144] = meta[rb * 4 + (t - 144)];

    const int sr = t >> 5, sg = t & 31;
    const int skst = sg >> 2, skq = sg & 3;
    const int slane = skq * 16 + sr;
    const int sdst = slane * 64 + ((skst ^ (sr & 7)) << 3);

    auto stage = [&](int k, int buf) {
        const float* src = poolf + ((size_t)k * 4096 + rb + sr) * 256 + sg * 8;
        f32x4 u0 = *(const f32x4*)src;
        f32x4 u1 = *(const f32x4*)(src + 4);
        union { unsigned short u[8]; frag f; } hu, lu;
        #pragma unroll
        for (int b = 0; b < 4; ++b) {
            split_bf(u0[b], hu.u[b], lu.u[b]);
            split_bf(u1[b], hu.u[b + 4], lu.u[b + 4]);
        }
        *(frag*)&Af[buf][0][sdst] = hu.f;
        *(frag*)&Af[buf][1][sdst] = lu.f;
    };

    stage(0, 0);
    __syncthreads();

    f32x4 acc[2];
    acc[0] = (f32x4)0.0f; acc[1] = (f32x4)0.0f;

    for (int k = 0; k < 8; ++k) {
        const int buf = k & 1;
        if (k < 7) stage(k + 1, buf ^ 1);
        #pragma unroll 2
        for (int kst = 0; kst < 8; ++kst) {
            int ao = ln * 64 + ((kst ^ (ln & 7)) << 3);
            frag ah = *(const frag*)&Af[buf][0][ao];
            frag al = *(const frag*)&Af[buf][1][ao];
            #pragma unroll
            for (int n = 0; n < 2; ++n) {
                size_t bo = (((size_t)k * 8 + kst) * 16 + (wv * 2 + n)) * 512 + ln * 8;
                frag bh = *(const frag*)(w2f_hi + bo);
                frag bl = *(const frag*)(w2f_lo + bo);
                acc[n] = __builtin_amdgcn_mfma_f32_16x16x32_bf16(ah, bh, acc[n], 0, 0, 0);
                acc[n] = __builtin_amdgcn_mfma_f32_16x16x32_bf16(al, bh, acc[n], 0, 0, 0);
                acc[n] = __builtin_amdgcn_mfma_f32_16x16x32_bf16(ah, bl, acc[n], 0, 0, 0);
            }
        }
        __syncthreads();
    }

    #pragma unroll
    for (int n = 0; n < 2; ++n) {
        int col = (wv * 2 + n) * 16 + lr16;
        float bks[8];
        #pragma unroll
        for (int k = 0; k < 8; ++k) bks[k] = b2[k * 256 + col] + kind_emb[k * 256 + col];
        #pragma unroll
        for (int r = 0; r < 4; ++r) {
            int row = kq * 4 + r;
            float hv = acc[n][r];
            #pragma unroll
            for (int k = 0; k < 8; ++k) hv = fmaf(cnt_s[row * 8 + k], bks[k], hv);
            hv *= den_s[row];
            hz[row * 256 + ((((col >> 2) ^ (row & 7)) << 2) | (col & 3))] = hv;
        }
    }
    __syncthreads();

    f32x4 az[2];
    az[0] = (f32x4)0.0f; az[1] = (f32x4)0.0f;

    for (int kst = 0; kst < 24; ++kst) {
        const int row = lr16;
        union { unsigned short u[8]; frag f; } hu, lu;
        if (kst < 8) {
            int c0 = kst * 8 + kq * 2;
            f32x4 u0 = *(const f32x4*)&hz[row * 256 + ((c0 ^ (row & 7)) << 2)];
            f32x4 u1 = *(const f32x4*)&hz[row * 256 + (((c0 + 1) ^ (row & 7)) << 2)];
            #pragma unroll
            for (int b = 0; b < 4; ++b) {
                split_bf(u0[b], hu.u[b], lu.u[b]);
                split_bf(u1[b], hu.u[b + 4], lu.u[b + 4]);
            }
        } else {
            const float* eb = (kst < 16) ? type_emb : layer_emb;
            const int* ids = (kst < 16) ? pt_s : lid_s;
            int ko = (kst & 7) * 32 + kq * 8;
            const float* sp = eb + (size_t)ids[row] * 256 + ko;
            f32x4 u0 = *(const f32x4*)sp;
            f32x4 u1 = *(const f32x4*)(sp + 4);
            #pragma unroll
            for (int b = 0; b < 4; ++b) {
                split_bf(u0[b], hu.u[b], lu.u[b]);
                split_bf(u1[b], hu.u[b + 4], lu.u[b + 4]);
            }
        }
        frag ah = hu.f, al = lu.f;
        #pragma unroll
        for (int n = 0; n < 2; ++n) {
            size_t bo = ((size_t)kst * 16 + (wv * 2 + n)) * 512 + ln * 8;
            frag bh = *(const frag*)(fw1f_hi + bo);
            frag bl = *(const frag*)(fw1f_lo + bo);
            az[n] = __builtin_amdgcn_mfma_f32_16x16x32_bf16(ah, bh, az[n], 0, 0, 0);
            az[n] = __builtin_amdgcn_mfma_f32_16x16x32_bf16(al, bh, az[n], 0, 0, 0);
            az[n] = __builtin_amdgcn_mfma_f32_16x16x32_bf16(ah, bl, az[n], 0, 0, 0);
        }
    }
    __syncthreads();

    #pragma unroll
    for (int n = 0; n < 2; ++n) {
        int col = (wv * 2 + n) * 16 + lr16;
        float fb1v = fb1[col];
        #pragma unroll
        for (int r = 0; r < 4; ++r) {
            int row = kq * 4 + r;
            float z = gelu_fast(az[n][r] + fb1v);
            hz[row * 256 + ((((col >> 2) ^ (row & 7)) << 2) | (col & 3))] = z;
        }
    }
    __syncthreads();

    f32x4 ao2[2];
    ao2[0] = (f32x4)0.0f; ao2[1] = (f32x4)0.0f;

    for (int kst = 0; kst < 8; ++kst) {
        const int row = lr16;
        int c0 = kst * 8 + kq * 2;
        f32x4 u0 = *(const f32x4*)&hz[row * 256 + ((c0 ^ (row & 7)) << 2)];
        f32x4 u1 = *(const f32x4*)&hz[row * 256 + (((c0 + 1) ^ (row & 7)) << 2)];
        union { unsigned short u[8]; frag f; } hu, lu;
        #pragma unroll
        for (int b = 0; b < 4; ++b) {
            split_bf(u0[b], hu.u[b], lu.u[b]);
            split_bf(u1[b], hu.u[b + 4], lu.u[b + 4]);
        }
        frag ah = hu.f, al = lu.f;
        #pragma unroll
        for (int n = 0; n < 2; ++n) {
            size_t bo = ((size_t)kst * 16 + (wv * 2 + n)) * 512 + ln * 8;
            frag bh = *(const frag*)(fw2f_hi + bo);
            frag bl = *(const frag*)(fw2f_lo + bo);
            ao2[n] = __builtin_amdgcn_mfma_f32_16x16x32_bf16(ah, bh, ao2[n], 0, 0, 0);
            ao2[n] = __builtin_amdgcn_mfma_f32_16x16x32_bf16(al, bh, ao2[n], 0, 0, 0);
            ao2[n] = __builtin_amdgcn_mfma_f32_16x16x32_bf16(ah, bl, ao2[n], 0, 0, 0);
        }
    }

    #pragma unroll
    for (int n = 0; n < 2; ++n) {
        int col = (wv * 2 + n) * 16 + lr16;
        float ob = fb2[col] + meta_b[col];
        float mw0 = meta_w[col], mw1 = meta_w[256 + col];
        float mw2 = meta_w[512 + col], mw3 = meta_w[768 + col];
        #pragma unroll
        for (int r = 0; r < 4; ++r) {
            int row = kq * 4 + r;
            float o = ao2[n][r] + ob;
            o = fmaf(meta_s[row * 4 + 0], mw0, o);
            o = fmaf(meta_s[row * 4 + 1], mw1, o);
            o = fmaf(meta_s[row * 4 + 2], mw2, o);
            o = fmaf(meta_s[row * 4 + 3], mw3, o);
            out[(size_t)(rb + row) * 256 + col] = o;
        }
    }
}

extern "C" void kernel_launch(void* const* d_in, const int* in_sizes, int n_in,
                              void* d_out, int out_size, void* d_ws, size_t ws_size,
                              hipStream_t stream) {
    const float* values    = (const float*)d_in[0];
    const int*   kinds     = (const int*)d_in[1];
    const int*   mask      = (const int*)d_in[2];
    const int*   prim_type = (const int*)d_in[3];
    const int*   layer_id  = (const int*)d_in[4];
    const float* meta      = (const float*)d_in[5];
    const float* B_ff      = (const float*)d_in[6];
    const float* kind_emb  = (const float*)d_in[7];
    const float* type_emb  = (const float*)d_in[8];
    const float* layer_emb = (const float*)d_in[9];
    const float* mlp_w1    = (const float*)d_in[10];
    const float* mlp_b1    = (const float*)d_in[11];
    const float* mlp_w2    = (const float*)d_in[12];
    const float* mlp_b2    = (const float*)d_in[13];
    const float* fuse_w1   = (const float*)d_in[14];
    const float* fuse_b1   = (const float*)d_in[15];
    const float* fuse_w2   = (const float*)d_in[16];
    const float* fuse_b2   = (const float*)d_in[17];
    const float* meta_w    = (const float*)d_in[18];
    const float* meta_b    = (const float*)d_in[19];

    short* ws    = (short*)d_ws;
    float* poolf = (float*)((char*)d_ws + POOL_BYTE);
    float* cntf  = (float*)((char*)d_ws + CNT_BYTE);
    float* denf  = (float*)((char*)d_ws + DEN_BYTE);
    float* out   = (float*)d_out;

    prep_kernel<<<224, 512, 0, stream>>>(mlp_w1, mlp_w2, fuse_w1, fuse_w2, ws);
    // ablation: front-only (pool zeros, overwritten by real run below)
    mlpfused_kernel<3><<<2048, 256, 0, stream>>>(values, kinds, mask, ws, B_ff,
                                                 mlp_b1, poolf, cntf, denf);
    // real
    mlpfused_kernel<0><<<2048, 256, 0, stream>>>(values, kinds, mask, ws, B_ff,
                                                 mlp_b1, poolf, cntf, denf);
    fuse_kernel<<<256, 512, 0, stream>>>(ws, poolf, cntf, denf, prim_type, layer_id,
                                         meta, type_emb, layer_emb, mlp_b2, kind_emb,
                                         fuse_b1, fuse_b2, meta_w, meta_b, out);
}

// Round 8
// 258.359 us; speedup vs baseline: 5.3720x; 1.1870x over previous
//
#include <hip/hip_runtime.h>
#include <math.h>

// PrimitiveTokenizer round 8: TWO launches total.
//  prep: 4 weight matrices -> bf16 hi/lo MFMA B-fragment planes in ws.
//  mono: 256 blocks x 512 thr, block = 16 rows = 1024 slots. Per block:
//        stage slots -> counts/denoms -> wave-0 ballot compaction (8 kinds,
//        16-padded, chunk descriptors) -> barrier-free chunk loop: FF computed
//        directly into A-fragment registers -> 6 MFMA x 16 nt -> gelu ->
//        LDS fp32 atomic pool[8 kinds][16 rows][260] (133 KB, block-local) ->
//        fuse phase A (sum_k pool[k] @ w2[k], A-frags read from fp32 pool with
//        in-register split) -> +cnt*(b2+kind_emb), /den -> hz (aliases pool) ->
//        phase B ([h|type_emb|layer_emb] @ fw1, gelu) -> phase C (@ fw2 +
//        meta linear) -> out. NO intermediate global traffic.

// ws layout (short element offsets)
#define W2F_HI   0
#define W2F_LO   524288
#define W1F_HI   1048576
#define W1F_LO   1179648
#define FW1F_HI  1310720
#define FW1F_LO  1507328
#define FW2F_HI  1703936
#define FW2F_LO  1769472

#define PSTR 260    // pool row stride (floats): 16B-aligned, modest bank spread

typedef __attribute__((ext_vector_type(8))) short frag;
typedef __attribute__((ext_vector_type(4))) float f32x4;

__device__ __forceinline__ unsigned short f2bf_rn(float x) {
    unsigned int u = __float_as_uint(x);
    unsigned int r = (u + 0x7fffu + ((u >> 16) & 1u)) >> 16;
    return (unsigned short)r;
}
__device__ __forceinline__ float bf2f(unsigned short h) {
    return __uint_as_float(((unsigned int)h) << 16);
}
__device__ __forceinline__ void split_bf(float x, unsigned short& h, unsigned short& l) {
    unsigned short hh = f2bf_rn(x);
    h = hh;
    l = f2bf_rn(x - bf2f(hh));
}

// |abs err| <= ~1.5e-7 (A&S 7.1.26 erf)
__device__ __forceinline__ float gelu_fast(float x) {
    float u = fabsf(x) * 0.7071067811865476f;
    float t = __builtin_amdgcn_rcpf(fmaf(0.3275911f, u, 1.0f));
    float p = fmaf(fmaf(fmaf(fmaf(1.061405429f, t, -1.453152027f), t,
                             1.421413741f), t, -0.284496736f), t, 0.254829592f) * t;
    float e = __expf(-u * u);
    float er = fmaf(-p, e, 1.0f);
    er = copysignf(er, x);
    return 0.5f * x * (1.0f + er);
}

// ---------------- prep: weights -> bf16 hi/lo fragment planes ----------------
__global__ __launch_bounds__(512) void prep_kernel(
    const float* __restrict__ w1, const float* __restrict__ w2,
    const float* __restrict__ fw1, const float* __restrict__ fw2,
    short* __restrict__ ws)
{
    int tid = blockIdx.x * 512 + threadIdx.x;
    int fid = tid >> 6, ln = tid & 63;
    if (fid >= 1792) return;
    int lr = ln & 15, kq = ln >> 4;
    float v[8];
    int dhi, dlo, dsto;
    if (fid < 1024) {                       // w2: [8k][8kst][16nt]
        int k = fid >> 7, kst = (fid >> 4) & 7, nt = fid & 15;
        int col = nt * 16 + lr;
        #pragma unroll
        for (int b = 0; b < 8; ++b) {
            int kg = kst * 32 + kq * 8 + b;
            v[b] = w2[(k * 256 + kg) * 256 + col];
        }
        dsto = fid * 512 + ln * 8; dhi = W2F_HI; dlo = W2F_LO;
    } else if (fid < 1280) {                // w1: [8k][2kst][16nt], K pad 48->64
        int f = fid - 1024;
        int k = f >> 5, kst = (f >> 4) & 1, nt = f & 15;
        int col = nt * 16 + lr;
        #pragma unroll
        for (int b = 0; b < 8; ++b) {
            int kg = kst * 32 + kq * 8 + b;
            v[b] = (kg < 48) ? w1[(k * 48 + kg) * 256 + col] : 0.0f;
        }
        dsto = f * 512 + ln * 8; dhi = W1F_HI; dlo = W1F_LO;
    } else if (fid < 1664) {                // fw1: [24kst][16nt]
        int f = fid - 1280;
        int kst = f >> 4, nt = f & 15;
        int col = nt * 16 + lr;
        #pragma unroll
        for (int b = 0; b < 8; ++b) {
            int kg = kst * 32 + kq * 8 + b;
            v[b] = fw1[kg * 256 + col];
        }
        dsto = f * 512 + ln * 8; dhi = FW1F_HI; dlo = FW1F_LO;
    } else {                                // fw2: [8kst][16nt]
        int f = fid - 1664;
        int kst = f >> 4, nt = f & 15;
        int col = nt * 16 + lr;
        #pragma unroll
        for (int b = 0; b < 8; ++b) {
            int kg = kst * 32 + kq * 8 + b;
            v[b] = fw2[kg * 256 + col];
        }
        dsto = f * 512 + ln * 8; dhi = FW2F_HI; dlo = FW2F_LO;
    }
    union { unsigned short u[8]; frag f; } hu, lu;
    #pragma unroll
    for (int b = 0; b < 8; ++b) split_bf(v[b], hu.u[b], lu.u[b]);
    *(frag*)(ws + dhi + dsto) = hu.f;
    *(frag*)(ws + dlo + dsto) = lu.f;
}

// ---------------- mono: MLP + pool + fuse, one block per 16 rows ----------------
__global__ __launch_bounds__(512, 1) void mono_kernel(
    const float* __restrict__ values, const int* __restrict__ kinds,
    const int* __restrict__ mask, const float* __restrict__ B_ff,
    const float* __restrict__ b1, const short* __restrict__ wsf,
    const int* __restrict__ pt, const int* __restrict__ lid,
    const float* __restrict__ meta, const float* __restrict__ type_emb,
    const float* __restrict__ layer_emb, const float* __restrict__ b2,
    const float* __restrict__ kind_emb, const float* __restrict__ fb1,
    const float* __restrict__ fb2, const float* __restrict__ meta_w,
    const float* __restrict__ meta_b, float* __restrict__ out)
{
    __shared__ __align__(16) float pool_ls[8 * 16 * PSTR];  // 133 KB; head aliased by hz
    __shared__ float vals_ls[1024];
    __shared__ unsigned char knd_ls[1024], msk_ls[1024];
    __shared__ unsigned short list[1152];
    __shared__ short chunk_kind[80], chunk_base[80];
    __shared__ int nch_s;
    __shared__ float b1_ls[2048];
    __shared__ float Bs_ls[24];
    __shared__ float cnt_ls[128], den_ls[16], meta_ls[64];
    __shared__ int pt_ls[16], lid_ls[16];

    const int t = threadIdx.x, blk = blockIdx.x;
    const int wv = t >> 6, ln = t & 63, lr16 = ln & 15, kq = ln >> 4;
    const int gbase = blk * 1024, rb = blk * 16;

    const short* w1f_hi  = wsf + W1F_HI;
    const short* w1f_lo  = wsf + W1F_LO;
    const short* w2f_hi  = wsf + W2F_HI;
    const short* w2f_lo  = wsf + W2F_LO;
    const short* fw1f_hi = wsf + FW1F_HI;
    const short* fw1f_lo = wsf + FW1F_LO;
    const short* fw2f_hi = wsf + FW2F_HI;
    const short* fw2f_lo = wsf + FW2F_LO;

    // ---- prologue: stage ----
    #pragma unroll
    for (int i = 0; i < 2; ++i) {
        int p = t + i * 512;
        vals_ls[p] = values[gbase + p];
        knd_ls[p]  = (unsigned char)kinds[gbase + p];
        msk_ls[p]  = (unsigned char)mask[gbase + p];
    }
    #pragma unroll
    for (int i = 0; i < 4; ++i) b1_ls[t + i * 512] = b1[t + i * 512];
    if (t < 24) Bs_ls[t] = B_ff[t];
    if (t >= 32 && t < 48) { pt_ls[t - 32] = pt[rb + t - 32]; lid_ls[t - 32] = lid[rb + t - 32]; }
    if (t >= 64 && t < 128) meta_ls[t - 64] = meta[rb * 4 + (t - 64)];
    for (int i = t; i < 8 * 16 * PSTR; i += 512) pool_ls[i] = 0.0f;
    __syncthreads();

    // ---- counts + denom: wave wv owns rows wv*2, wv*2+1 ----
    #pragma unroll
    for (int j = 0; j < 2; ++j) {
        int r = wv * 2 + j;
        int kd = knd_ls[r * 64 + ln], mk = msk_ls[r * 64 + ln];
        unsigned long long balm = __ballot(mk != 0);
        int myc = 0;
        #pragma unroll
        for (int k = 0; k < 8; ++k) {
            unsigned long long bal = __ballot(mk && (kd == k));
            int c = __popcll(bal);
            myc = (ln == k) ? c : myc;
        }
        if (ln < 8) cnt_ls[r * 8 + ln] = (float)myc;
        if (ln == 0) {
            int tot = __popcll(balm);
            den_ls[r] = 1.0f / (float)(tot > 0 ? tot : 1);
        }
    }

    // ---- deterministic 8-kind compaction (wave 0), 16-padded + chunk desc ----
    if (t < 64) {
        int cnts[8];
        #pragma unroll
        for (int k = 0; k < 8; ++k) cnts[k] = 0;
        for (int c = 0; c < 16; ++c) {
            int p = c * 64 + t;
            int kd = knd_ls[p], mk = msk_ls[p];
            #pragma unroll
            for (int k = 0; k < 8; ++k) {
                unsigned long long bal = __ballot(mk && (kd == k));
                cnts[k] += __popcll(bal);
            }
        }
        int offk[8], run = 0;
        #pragma unroll
        for (int k = 0; k < 8; ++k) { offk[k] = run; run += (cnts[k] + 15) & ~15; }
        int fillk[8];
        #pragma unroll
        for (int k = 0; k < 8; ++k) fillk[k] = 0;
        const unsigned long long below = (1ull << t) - 1ull;
        for (int c = 0; c < 16; ++c) {
            int p = c * 64 + t;
            int kd = knd_ls[p], mk = msk_ls[p];
            #pragma unroll
            for (int k = 0; k < 8; ++k) {
                unsigned long long bal = __ballot(mk && (kd == k));
                if (mk && (kd == k)) {
                    int rank = __popcll(bal & below);
                    list[offk[k] + fillk[k] + rank] = (unsigned short)p;
                }
                fillk[k] += __popcll(bal);
            }
        }
        #pragma unroll
        for (int k = 0; k < 8; ++k) {
            int padded = (cnts[k] + 15) & ~15;
            for (int i = cnts[k] + t; i < padded; i += 64) list[offk[k] + i] = 0xFFFFu;
        }
        if (t == 0) {
            int ci = 0;
            #pragma unroll
            for (int k = 0; k < 8; ++k) {
                int nk = (cnts[k] + 15) >> 4;
                for (int j = 0; j < nk; ++j) {
                    chunk_kind[ci] = (short)k;
                    chunk_base[ci] = (short)(offk[k] + j * 16);
                    ++ci;
                }
            }
            nch_s = ci;
        }
    }
    __syncthreads();

    // ---- barrier-free MLP loop: waves stride chunks ----
    const int nch = nch_s;
    for (int m = wv; m < nch; m += 8) {
        const int k = (int)chunk_kind[m];
        const int cb = (int)chunk_base[m];
        int slot = list[cb + lr16];
        float v = vals_ls[slot & 1023];
        v = (slot == 0xFFFF) ? 0.0f : v;

        // FF directly into A-frag registers: lane(lr16,kq) = A[slot=lr16][kst*32+kq*8+b]
        frag ah[2], al[2];
        #pragma unroll
        for (int kst = 0; kst < 2; ++kst) {
            union { unsigned short u[8]; frag f; } hu, lu;
            int jb0 = kst * 32 + kq * 8;
            #pragma unroll
            for (int b = 0; b < 8; ++b) {
                int jb = jb0 + b;
                float sv;
                if (jb < 48) {
                    int jm = (jb < 24) ? jb : jb - 24;
                    float cadd = (jb < 24) ? 0.0f : 0.25f;   // cos = sin(x + 1/4 rev)
                    float rev = __builtin_amdgcn_fractf(fmaf(v, Bs_ls[jm], cadd));
                    sv = __builtin_amdgcn_sinf(rev);
                } else {
                    sv = 0.0f;                               // K-pad 48..63
                }
                split_bf(sv, hu.u[b], lu.u[b]);
            }
            ah[kst] = hu.f; al[kst] = lu.f;
        }

        int e4[4];
        #pragma unroll
        for (int r = 0; r < 4; ++r) {
            int sl = list[cb + kq * 4 + r];
            e4[r] = (sl == 0xFFFF) ? -1 : ((sl >> 6) & 15);
        }

        #pragma unroll 4
        for (int nt = 0; nt < 16; ++nt) {
            int o0 = ((k * 2 + 0) * 16 + nt) * 512 + ln * 8;
            int o1 = ((k * 2 + 1) * 16 + nt) * 512 + ln * 8;
            frag bh0 = *(const frag*)(w1f_hi + o0);
            frag bl0 = *(const frag*)(w1f_lo + o0);
            frag bh1 = *(const frag*)(w1f_hi + o1);
            frag bl1 = *(const frag*)(w1f_lo + o1);
            f32x4 acc = (f32x4)0.0f;
            acc = __builtin_amdgcn_mfma_f32_16x16x32_bf16(ah[0], bh0, acc, 0, 0, 0);
            acc = __builtin_amdgcn_mfma_f32_16x16x32_bf16(al[0], bh0, acc, 0, 0, 0);
            acc = __builtin_amdgcn_mfma_f32_16x16x32_bf16(ah[0], bl0, acc, 0, 0, 0);
            acc = __builtin_amdgcn_mfma_f32_16x16x32_bf16(ah[1], bh1, acc, 0, 0, 0);
            acc = __builtin_amdgcn_mfma_f32_16x16x32_bf16(al[1], bh1, acc, 0, 0, 0);
            acc = __builtin_amdgcn_mfma_f32_16x16x32_bf16(ah[1], bl1, acc, 0, 0, 0);
            float b1v = b1_ls[k * 256 + nt * 16 + lr16];
            #pragma unroll
            for (int r = 0; r < 4; ++r) {
                if (e4[r] >= 0) {
                    float g = gelu_fast(acc[r] + b1v);
                    atomicAdd(&pool_ls[(k * 16 + e4[r]) * PSTR + nt * 16 + lr16], g);
                }
            }
        }
    }
    __syncthreads();

    // ---- fuse phase A: acc = sum_k pool[k] @ w2[k]  (A-frags from fp32 pool) ----
    f32x4 acc[2];
    acc[0] = (f32x4)0.0f; acc[1] = (f32x4)0.0f;

    for (int k = 0; k < 8; ++k) {
        #pragma unroll 2
        for (int kst = 0; kst < 8; ++kst) {
            const float* pp = &pool_ls[(k * 16 + lr16) * PSTR + kst * 32 + kq * 8];
            f32x4 u0 = *(const f32x4*)pp;
            f32x4 u1 = *(const f32x4*)(pp + 4);
            union { unsigned short u[8]; frag f; } hu, lu;
            #pragma unroll
            for (int b = 0; b < 4; ++b) {
                split_bf(u0[b], hu.u[b], lu.u[b]);
                split_bf(u1[b], hu.u[b + 4], lu.u[b + 4]);
            }
            frag ah = hu.f, al = lu.f;
            #pragma unroll
            for (int n = 0; n < 2; ++n) {
                int bo = ((k * 8 + kst) * 16 + (wv * 2 + n)) * 512 + ln * 8;
                frag bh = *(const frag*)(w2f_hi + bo);
                frag bl = *(const frag*)(w2f_lo + bo);
                acc[n] = __builtin_amdgcn_mfma_f32_16x16x32_bf16(ah, bh, acc[n], 0, 0, 0);
                acc[n] = __builtin_amdgcn_mfma_f32_16x16x32_bf16(al, bh, acc[n], 0, 0, 0);
                acc[n] = __builtin_amdgcn_mfma_f32_16x16x32_bf16(ah, bl, acc[n], 0, 0, 0);
            }
        }
    }
    __syncthreads();     // all pool reads done; hz may alias pool head

    float* hz = pool_ls; // [16][256] granule-XOR swizzled

    // ---- epilogue A: + cnt*(b2+kind_emb), * den -> hz ----
    #pragma unroll
    for (int n = 0; n < 2; ++n) {
        int col = (wv * 2 + n) * 16 + lr16;
        float bks[8];
        #pragma unroll
        for (int k = 0; k < 8; ++k) bks[k] = b2[k * 256 + col] + kind_emb[k * 256 + col];
        #pragma unroll
        for (int r = 0; r < 4; ++r) {
            int row = kq * 4 + r;
            float hv = acc[n][r];
            #pragma unroll
            for (int k = 0; k < 8; ++k) hv = fmaf(cnt_ls[row * 8 + k], bks[k], hv);
            hv *= den_ls[row];
            hz[row * 256 + ((((col >> 2) ^ (row & 7)) << 2) | (col & 3))] = hv;
        }
    }
    __syncthreads();

    // ---- phase B: z_pre = [h | type_emb | layer_emb] @ fw1 (K=768) ----
    f32x4 az[2];
    az[0] = (f32x4)0.0f; az[1] = (f32x4)0.0f;

    for (int kst = 0; kst < 24; ++kst) {
        const int row = lr16;
        union { unsigned short u[8]; frag f; } hu, lu;
        if (kst < 8) {
            int c0 = kst * 8 + kq * 2;
            f32x4 u0 = *(const f32x4*)&hz[row * 256 + ((c0 ^ (row & 7)) << 2)];
            f32x4 u1 = *(const f32x4*)&hz[row * 256 + (((c0 + 1) ^ (row & 7)) << 2)];
            #pragma unroll
            for (int b = 0; b < 4; ++b) {
                split_bf(u0[b], hu.u[b], lu.u[b]);
                split_bf(u1[b], hu.u[b + 4], lu.u[b + 4]);
            }
        } else {
            const float* eb = (kst < 16) ? type_emb : layer_emb;
            const int* ids = (kst < 16) ? pt_ls : lid_ls;
            int ko = (kst & 7) * 32 + kq * 8;
            const float* sp = eb + (size_t)ids[row] * 256 + ko;
            f32x4 u0 = *(const f32x4*)sp;
            f32x4 u1 = *(const f32x4*)(sp + 4);
            #pragma unroll
            for (int b = 0; b < 4; ++b) {
                split_bf(u0[b], hu.u[b], lu.u[b]);
                split_bf(u1[b], hu.u[b + 4], lu.u[b + 4]);
            }
        }
        frag ah = hu.f, al = lu.f;
        #pragma unroll
        for (int n = 0; n < 2; ++n) {
            int bo = (kst * 16 + (wv * 2 + n)) * 512 + ln * 8;
            frag bh = *(const frag*)(fw1f_hi + bo);
            frag bl = *(const frag*)(fw1f_lo + bo);
            az[n] = __builtin_amdgcn_mfma_f32_16x16x32_bf16(ah, bh, az[n], 0, 0, 0);
            az[n] = __builtin_amdgcn_mfma_f32_16x16x32_bf16(al, bh, az[n], 0, 0, 0);
            az[n] = __builtin_amdgcn_mfma_f32_16x16x32_bf16(ah, bl, az[n], 0, 0, 0);
        }
    }
    __syncthreads();     // all hz reads done

    #pragma unroll
    for (int n = 0; n < 2; ++n) {
        int col = (wv * 2 + n) * 16 + lr16;
        float fb1v = fb1[col];
        #pragma unroll
        for (int r = 0; r < 4; ++r) {
            int row = kq * 4 + r;
            float z = gelu_fast(az[n][r] + fb1v);
            hz[row * 256 + ((((col >> 2) ^ (row & 7)) << 2) | (col & 3))] = z;
        }
    }
    __syncthreads();

    // ---- phase C: out = z @ fw2 + fb2 + meta @ meta_w + meta_b ----
    f32x4 ao2[2];
    ao2[0] = (f32x4)0.0f; ao2[1] = (f32x4)0.0f;

    for (int kst = 0; kst < 8; ++kst) {
        const int row = lr16;
        int c0 = kst * 8 + kq * 2;
        f32x4 u0 = *(const f32x4*)&hz[row * 256 + ((c0 ^ (row & 7)) << 2)];
        f32x4 u1 = *(const f32x4*)&hz[row * 256 + (((c0 + 1) ^ (row & 7)) << 2)];
        union { unsigned short u[8]; frag f; } hu, lu;
        #pragma unroll
        for (int b = 0; b < 4; ++b) {
            split_bf(u0[b], hu.u[b], lu.u[b]);
            split_bf(u1[b], hu.u[b + 4], lu.u[b + 4]);
        }
        frag ah = hu.f, al = lu.f;
        #pragma unroll
        for (int n = 0; n < 2; ++n) {
            int bo = (kst * 16 + (wv * 2 + n)) * 512 + ln * 8;
            frag bh = *(const frag*)(fw2f_hi + bo);
            frag bl = *(const frag*)(fw2f_lo + bo);
            ao2[n] = __builtin_amdgcn_mfma_f32_16x16x32_bf16(ah, bh, ao2[n], 0, 0, 0);
            ao2[n] = __builtin_amdgcn_mfma_f32_16x16x32_bf16(al, bh, ao2[n], 0, 0, 0);
            ao2[n] = __builtin_amdgcn_mfma_f32_16x16x32_bf16(ah, bl, ao2[n], 0, 0, 0);
        }
    }

    #pragma unroll
    for (int n = 0; n < 2; ++n) {
        int col = (wv * 2 + n) * 16 + lr16;
        float ob = fb2[col] + meta_b[col];
        float mw0 = meta_w[col], mw1 = meta_w[256 + col];
        float mw2 = meta_w[512 + col], mw3 = meta_w[768 + col];
        #pragma unroll
        for (int r = 0; r < 4; ++r) {
            int row = kq * 4 + r;
            float o = ao2[n][r] + ob;
            o = fmaf(meta_ls[row * 4 + 0], mw0, o);
            o = fmaf(meta_ls[row * 4 + 1], mw1, o);
            o = fmaf(meta_ls[row * 4 + 2], mw2, o);
            o = fmaf(meta_ls[row * 4 + 3], mw3, o);
            out[(size_t)(rb + row) * 256 + col] = o;
        }
    }
}

extern "C" void kernel_launch(void* const* d_in, const int* in_sizes, int n_in,
                              void* d_out, int out_size, void* d_ws, size_t ws_size,
                              hipStream_t stream) {
    const float* values    = (const float*)d_in[0];
    const int*   kinds     = (const int*)d_in[1];
    const int*   mask      = (const int*)d_in[2];
    const int*   prim_type = (const int*)d_in[3];
    const int*   layer_id  = (const int*)d_in[4];
    const float* meta      = (const float*)d_in[5];
    const float* B_ff      = (const float*)d_in[6];
    const float* kind_emb  = (const float*)d_in[7];
    const float* type_emb  = (const float*)d_in[8];
    const float* layer_emb = (const float*)d_in[9];
    const float* mlp_w1    = (const float*)d_in[10];
    const float* mlp_b1    = (const float*)d_in[11];
    const float* mlp_w2    = (const float*)d_in[12];
    const float* mlp_b2    = (const float*)d_in[13];
    const float* fuse_w1   = (const float*)d_in[14];
    const float* fuse_b1   = (const float*)d_in[15];
    const float* fuse_w2   = (const float*)d_in[16];
    const float* fuse_b2   = (const float*)d_in[17];
    const float* meta_w    = (const float*)d_in[18];
    const float* meta_b    = (const float*)d_in[19];

    short* ws  = (short*)d_ws;
    float* out = (float*)d_out;

    prep_kernel<<<224, 512, 0, stream>>>(mlp_w1, mlp_w2, fuse_w1, fuse_w2, ws);
    mono_kernel<<<256, 512, 0, stream>>>(values, kinds, mask, B_ff, mlp_b1, ws,
                                         prim_type, layer_id, meta, type_emb,
                                         layer_emb, mlp_b2, kind_emb, fuse_b1,
                                         fuse_b2, meta_w, meta_b, out);
}